// Round 3
// baseline (746.246 us; speedup 1.0000x reference)
//
#include <hip/hip_runtime.h>
#include <hip/hip_bf16.h>

// B=4, S=2048, D=768, H=12, DH=64
// out = [ ctx (B*S*D fp32) | probs (B*H*S*S fp32) ]
#define BB 4
#define SS 2048
#define DD 768
#define HH 12

typedef unsigned short u16t;
typedef unsigned char  u8t;
typedef unsigned int   u32t;
typedef __attribute__((ext_vector_type(8)))  short bf16x8;
typedef __attribute__((ext_vector_type(4)))  float f32x4;
typedef __attribute__((ext_vector_type(16))) float f32x16;

union FragU { bf16x8 v; ushort4 h[2]; uint4 u; u32t g[4]; };

__device__ __forceinline__ u16t f2bf(float f) {
  union { float fv; u32t u; } x; x.fv = f;
  u32t r = x.u + 0x7FFFu + ((x.u >> 16) & 1u);   // RNE f32 -> bf16
  return (u16t)(r >> 16);
}

__device__ __forceinline__ u32t pkbf2(float a, float b) {  // 2xf32 -> packed bf16x2
  __hip_bfloat162 h2 = __float22bfloat162_rn(make_float2(a, b));
  union { __hip_bfloat162 h; u32t u; } c; c.h = h2;
  return c.u;
}

// pack 4 bool bytes (0/1) of a u32 into bits 0..3
__device__ __forceinline__ u32t pack4(u32t w) {
  return ((w & 0x01010101u) * 0x01020408u) >> 24;
}
__device__ __forceinline__ u32t pack16b(uint4 v) {  // 16 bool bytes -> 16 bits
  return pack4(v.x) | (pack4(v.y) << 4) | (pack4(v.z) << 8) | (pack4(v.w) << 12);
}
__device__ __forceinline__ u32t pack_i4(int4 v) {
  return (v.x ? 1u : 0u) | ((v.y ? 1u : 0u) << 1) | ((v.z ? 1u : 0u) << 2) | ((v.w ? 1u : 0u) << 3);
}
__device__ __forceinline__ u32t pack_f4(float4 v) {
  return (v.x != 0.f ? 1u : 0u) | ((v.y != 0.f ? 1u : 0u) << 1) |
         ((v.z != 0.f ? 1u : 0u) << 2) | ((v.w != 0.f ? 1u : 0u) << 3);
}

// per-lane mask tile: 128 bits (4 words of 32 k) for one q-row at col kt*128
__device__ __forceinline__ uint4 load_mask_tile(const void* __restrict__ maskp,
                                                int fmt, size_t ebase)
{
  uint4 r;
  if (fmt == 1) {
    const uint4* s = (const uint4*)((const u8t*)maskp + ebase);
    uint4 a0 = s[0], a1 = s[1], a2 = s[2], a3 = s[3];
    uint4 a4 = s[4], a5 = s[5], a6 = s[6], a7 = s[7];
    r.x = pack16b(a0) | (pack16b(a1) << 16);
    r.y = pack16b(a2) | (pack16b(a3) << 16);
    r.z = pack16b(a4) | (pack16b(a5) << 16);
    r.w = pack16b(a6) | (pack16b(a7) << 16);
  } else if (fmt == 0) {
    const int4* s = (const int4*)((const int*)maskp + ebase);
    u32t wds[4];
#pragma unroll
    for (int c = 0; c < 4; ++c) {
      u32t a = 0;
#pragma unroll
      for (int j = 0; j < 8; ++j) a |= pack_i4(s[c * 8 + j]) << (j * 4);
      wds[c] = a;
    }
    r.x = wds[0]; r.y = wds[1]; r.z = wds[2]; r.w = wds[3];
  } else {
    const float4* s = (const float4*)((const float*)maskp + ebase);
    u32t wds[4];
#pragma unroll
    for (int c = 0; c < 4; ++c) {
      u32t a = 0;
#pragma unroll
      for (int j = 0; j < 8; ++j) a |= pack_f4(s[c * 8 + j]) << (j * 4);
      wds[c] = a;
    }
    r.x = wds[0]; r.y = wds[1]; r.z = wds[2]; r.w = wds[3];
  }
  return r;
}

// ---- mask dtype detector: flag = 0 int32(0/1), 1 bool bytes, 2 float32(0/1) ----
__global__ void detect_kernel(const u32t* __restrict__ mp, int* __restrict__ flag)
{
  __shared__ int s_isb, s_isf;
  if (threadIdx.x == 0) { s_isb = 0; s_isf = 0; }
  __syncthreads();
  int isb = 0, isf = 0;
  for (int i = threadIdx.x; i < 16384; i += 256) {
    u32t v = mp[i];
    if ((v & 0xFF000000u) == 0x3F000000u) isf = 1;
    else if (v & 0xFFFFFF00u) isb = 1;
  }
  if (isb) atomicOr(&s_isb, 1);
  if (isf) atomicOr(&s_isf, 1);
  __syncthreads();
  if (threadIdx.x == 0) *flag = s_isf ? 2 : (s_isb ? 1 : 0);
}

// ---- shared GEMM tile: acc[8] = X[m0..+64][:] @ W[:][n0..+128] (bf16 MFMA) ----
__device__ __forceinline__ void proj_tile_gemm(const float* __restrict__ X,
    const float* __restrict__ W, int m0, int n0, int t,
    u16t* __restrict__ Al, u16t* __restrict__ Bl, f32x4 acc[8])
{
  const int w = t >> 6, l = t & 63;
  const int lq = l & 15, lg = l >> 4;
  const int ar = t >> 2, ac = (t & 3) * 8;
  const int bn = (t & 15) * 8;

  for (int kk = 0; kk < DD; kk += 32) {
    {
      const float* s = X + (size_t)(m0 + ar) * DD + kk + ac;
      float4 f0 = *(const float4*)s;
      float4 f1 = *(const float4*)(s + 4);
      u16t* d = &Al[ar * 40 + ac];
      d[0] = f2bf(f0.x); d[1] = f2bf(f0.y); d[2] = f2bf(f0.z); d[3] = f2bf(f0.w);
      d[4] = f2bf(f1.x); d[5] = f2bf(f1.y); d[6] = f2bf(f1.z); d[7] = f2bf(f1.w);
    }
#pragma unroll
    for (int rep = 0; rep < 2; ++rep) {
      const int c = (t >> 4) + rep * 16;
      const float* s = W + (size_t)(kk + c) * DD + n0 + bn;
      float4 f0 = *(const float4*)s;
      float4 f1 = *(const float4*)(s + 4);
      float fv[8] = {f0.x, f0.y, f0.z, f0.w, f1.x, f1.y, f1.z, f1.w};
#pragma unroll
      for (int e = 0; e < 8; ++e) {
        const int n = bn + e;
        Bl[n * 40 + (c ^ (((n >> 3) & 3) * 8))] = f2bf(fv[e]);
      }
    }
    __syncthreads();
    FragU a;
    const int arow = w * 16 + lq;
    a.h[0] = *(const ushort4*)&Al[arow * 40 + 4 * lg];
    a.h[1] = *(const ushort4*)&Al[arow * 40 + 4 * lg + 16];
#pragma unroll
    for (int nt = 0; nt < 8; ++nt) {
      const int bcol = nt * 16 + lq;
      const int xb = ((bcol >> 3) & 3) * 8;
      FragU bfr;
      bfr.h[0] = *(const ushort4*)&Bl[bcol * 40 + ((4 * lg) ^ xb)];
      bfr.h[1] = *(const ushort4*)&Bl[bcol * 40 + ((4 * lg + 16) ^ xb)];
      acc[nt] = __builtin_amdgcn_mfma_f32_16x16x32_bf16(a.v, bfr.v, acc[nt], 0, 0, 0);
    }
    __syncthreads();
  }
}

// ---- proj Q/K: out layout [b][h][s][64] bf16 ----
__global__ __launch_bounds__(256)
void proj_qk_kernel(const float* __restrict__ X, const float* __restrict__ W,
                    const float* __restrict__ bias, u16t* __restrict__ out)
{
  __shared__ u16t Al[64 * 40];
  __shared__ u16t Bl[128 * 40];
  const int t = threadIdx.x;
  const int w = t >> 6, l = t & 63;
  const int lq = l & 15, lg = l >> 4;
  const int m0 = blockIdx.x * 64;
  const int n0 = blockIdx.y * 128;
  const int b = m0 >> 11;

  f32x4 acc[8];
#pragma unroll
  for (int i = 0; i < 8; ++i)
#pragma unroll
    for (int r = 0; r < 4; ++r) acc[i][r] = 0.f;

  proj_tile_gemm(X, W, m0, n0, t, Al, Bl, acc);

#pragma unroll
  for (int nt = 0; nt < 8; ++nt) {
    const int n = n0 + nt * 16 + lq;
    const int h = n >> 6, dh = n & 63;
    const float bb = bias[n];
#pragma unroll
    for (int r = 0; r < 4; ++r) {
      const int s = (m0 & 2047) + w * 16 + 4 * lg + r;
      out[((size_t)(b * HH + h) * SS + s) * 64 + dh] = f2bf(acc[nt][r] + bb);
    }
  }
}

// ---- proj V: out layout [b][h][dh][s] bf16 (transposed via LDS) ----
__global__ __launch_bounds__(256)
void proj_v_kernel(const float* __restrict__ X, const float* __restrict__ W,
                   const float* __restrict__ bias, u16t* __restrict__ out)
{
  __shared__ u16t Al[64 * 40];
  __shared__ u16t Bl[128 * 40];
  __shared__ u16t Tl[128 * 72];    // [n-local][m-local], padded to 72
  const int t = threadIdx.x;
  const int w = t >> 6, l = t & 63;
  const int lq = l & 15, lg = l >> 4;
  const int m0 = blockIdx.x * 64;
  const int n0 = blockIdx.y * 128;
  const int b = m0 >> 11;

  f32x4 acc[8];
#pragma unroll
  for (int i = 0; i < 8; ++i)
#pragma unroll
    for (int r = 0; r < 4; ++r) acc[i][r] = 0.f;

  proj_tile_gemm(X, W, m0, n0, t, Al, Bl, acc);

#pragma unroll
  for (int nt = 0; nt < 8; ++nt) {
    const float bb = bias[n0 + nt * 16 + lq];
#pragma unroll
    for (int r = 0; r < 4; ++r)
      Tl[(nt * 16 + lq) * 72 + w * 16 + 4 * lg + r] = f2bf(acc[nt][r] + bb);
  }
  __syncthreads();

  const int rowl = t >> 1;              // n-local 0..127
  const int half = t & 1;               // s-half
  const int ncol = n0 + rowl;
  const int h = ncol >> 6, dh = ncol & 63;
  const int s = (m0 & 2047) + half * 32;
  u16t* dst = out + ((size_t)(b * HH + h) * 64 + dh) * SS + s;
#pragma unroll
  for (int i = 0; i < 4; ++i) {
    uint4 vv = *(const uint4*)&Tl[rowl * 72 + half * 32 + i * 8];
    *(uint4*)(dst + i * 8) = vv;
  }
}

// ---- fused attention: 32x32x16 MFMA, 4 waves x 32 q-rows, dbuf K DMA ----
// Swapped QK^T (A=K, B=Q): acc[r] = S[k = c*32 + (r&3)+8*(r>>2)+4*hh][q = qbase+lq]
__global__ __launch_bounds__(256, 3)
void attn_kernel(const u16t* __restrict__ Qh, const u16t* __restrict__ Kh,
                 const u16t* __restrict__ Vh, const void* __restrict__ maskp,
                 const int* __restrict__ flagp,
                 float* __restrict__ ctx, float* __restrict__ probs)
{
  __shared__ u16t Kl[2][128 * 64];   // [kr][dh ^ ((kr&7)*8)], dbuf, 32 KB
  __shared__ u16t Vt[64 * 128];      // [dh][kr ^ ((dh&7)*8)], 16 KB

  const int t = threadIdx.x;
  const int w = t >> 6, l = t & 63;
  const int lq = l & 31;     // q-col / A-row within 32
  const int hh = l >> 5;     // lane half

  const int bid = (int)blockIdx.x;             // 0..767
  const int lid = (bid & 7) * 96 + (bid >> 3); // bijective XCD chunking
  const int bh = lid >> 4;                     // 0..47
  const int qt = lid & 15;
  const int b = bh / HH;
  const int fmt = *flagp;
  const int qbase = qt * 128 + w * 32;

  const u16t* qh = Qh + (size_t)bh * SS * 64;
  const u16t* kh = Kh + (size_t)bh * SS * 64;
  const u16t* vh = Vh + (size_t)bh * SS * 64;

  // Q fragments (B operand): slot (hh,j) = Q[qbase+lq][dhc*16 + 8*hh + j]
  FragU bq[4];
  {
    const u16t* qp = qh + (size_t)(qbase + lq) * 64 + 8 * hh;
#pragma unroll
    for (int dhc = 0; dhc < 4; ++dhc) bq[dhc].u = *(const uint4*)(qp + dhc * 16);
  }

  // staging coords
  const int krA = l >> 3;            // K: row within 8-group
  const int kcA = (l & 7) * 8;       // K: col elems
  const int vdA = l >> 4;            // V: row within 4-group
  const int vcA = (l & 15) * 8;      // V: col elems

#define STAGE_K(kt_, buf_)                                                       \
  _Pragma("unroll")                                                              \
  for (int j = 0; j < 4; ++j) {                                                  \
    const int kr = (w * 4 + j) * 8 + krA;                                        \
    const u16t* gsrc = kh + (size_t)((kt_) * 128 + kr) * 64 + (kcA ^ ((kr & 7) * 8)); \
    __builtin_amdgcn_global_load_lds(                                            \
        (const __attribute__((address_space(1))) void*)gsrc,                     \
        (__attribute__((address_space(3))) void*)(&Kl[buf_][(w * 4 + j) * 512]), \
        16, 0, 0);                                                               \
  }

#define STAGE_V(kt_)                                                             \
  _Pragma("unroll")                                                              \
  for (int j = 0; j < 4; ++j) {                                                  \
    const int dv = (w * 4 + j) * 4 + vdA;                                        \
    const u16t* gsrc = vh + (size_t)dv * SS + (kt_) * 128 + (vcA ^ ((dv & 7) * 8)); \
    __builtin_amdgcn_global_load_lds(                                            \
        (const __attribute__((address_space(1))) void*)gsrc,                     \
        (__attribute__((address_space(3))) void*)(&Vt[(w * 4 + j) * 512]),       \
        16, 0, 0);                                                               \
  }

  // QK^T chunk: 4 MFMA over dh=64, A=K from LDS, B=Q regs
#define QKT_CHUNK(c_, buf_, accv)                                                \
  _Pragma("unroll")                                                              \
  for (int i = 0; i < 16; ++i) (accv)[i] = 0.f;                                  \
  _Pragma("unroll")                                                              \
  for (int dhc = 0; dhc < 4; ++dhc) {                                            \
    const int kr = (c_) * 32 + lq;                                               \
    FragU ak;                                                                    \
    ak.u = *(const uint4*)&Kl[buf_][kr * 64 + (((dhc * 16 + 8 * hh)) ^ ((kr & 7) * 8))]; \
    (accv) = __builtin_amdgcn_mfma_f32_32x32x16_bf16(ak.v, bq[dhc].v, (accv), 0, 0, 0); \
  }

  float m = -3.0e38f, sm = 0.f;
  const size_t mrowbase = (size_t)b * SS * SS + (size_t)(qbase + lq) * SS;

  // prologue: K(0)
  STAGE_K(0, 0)
  asm volatile("s_waitcnt vmcnt(0)" ::: "memory");
  __syncthreads();

  // ---------------- sweep 1: online row max & exp-sum ----------------
  for (int kt = 0; kt < 16; ++kt) {
    const int cur = kt & 1;
    const int ktn = (kt + 1) & 15;          // 15 -> 0 (prefetch for sweep 2)
    STAGE_K(ktn, cur ^ 1)
    uint4 mw = load_mask_tile(maskp, fmt, mrowbase + kt * 128);
    u32t mwv[4] = {mw.x, mw.y, mw.z, mw.w};
#pragma unroll
    for (int c = 0; c < 4; ++c) {
      f32x16 acc;
      QKT_CHUNK(c, cur, acc)
      float scv[16];
      float tm = -3.0e38f;
#pragma unroll
      for (int r = 0; r < 16; ++r) {
        float s = acc[r] * 0.125f;
        if ((mwv[c] >> ((r & 3) + 8 * (r >> 2) + 4 * hh)) & 1) s = -1.0e9f;
        scv[r] = s;
        tm = fmaxf(tm, s);
      }
      tm = fmaxf(tm, __shfl_xor(tm, 32));
      const float nm = fmaxf(m, tm);
      float ss = 0.f;
#pragma unroll
      for (int r = 0; r < 16; ++r) ss += __expf(scv[r] - nm);
      ss += __shfl_xor(ss, 32);
      sm = sm * __expf(m - nm) + ss;
      m = nm;
    }
    asm volatile("s_waitcnt vmcnt(0)" ::: "memory");
    __syncthreads();
  }

  const float inv = 1.0f / sm;
  f32x16 acco[2];
#pragma unroll
  for (int i = 0; i < 16; ++i) { acco[0][i] = 0.f; acco[1][i] = 0.f; }

  // ---------------- sweep 2: recompute -> probs + PV ----------------
  for (int kt = 0; kt < 16; ++kt) {
    const int cur = kt & 1;
    STAGE_V(kt)
    if (kt < 15) { STAGE_K(kt + 1, cur ^ 1) }
    uint4 mw = load_mask_tile(maskp, fmt, mrowbase + kt * 128);
    u32t mwv[4] = {mw.x, mw.y, mw.z, mw.w};
    const size_t prow = ((size_t)bh * SS + qbase + lq) * SS + kt * 128;

    FragU pf[4][2];
#pragma unroll
    for (int c = 0; c < 4; ++c) {
      f32x16 acc;
      QKT_CHUNK(c, cur, acc)
      float p[16];
#pragma unroll
      for (int r = 0; r < 16; ++r) {
        float s = acc[r] * 0.125f;
        if ((mwv[c] >> ((r & 3) + 8 * (r >> 2) + 4 * hh)) & 1) s = -1.0e9f;
        p[r] = __expf(s - m) * inv;
      }
      // probs: float4 per reg-quad; k = c*32 + (r&3) + 8*(r>>2) + 4*hh
#pragma unroll
      for (int g = 0; g < 4; ++g) {
        float4 f4;
        f4.x = p[4 * g + 0]; f4.y = p[4 * g + 1];
        f4.z = p[4 * g + 2]; f4.w = p[4 * g + 3];
        *(float4*)(probs + prow + c * 32 + 8 * g + 4 * hh) = f4;
      }
      // build PV B-fragments: exchange halves, pack to bf16
      float y[8];
#pragma unroll
      for (int j = 0; j < 4; ++j) y[j] = __shfl_xor(hh ? p[j] : p[4 + j], 32);
#pragma unroll
      for (int j = 0; j < 4; ++j) y[4 + j] = __shfl_xor(hh ? p[8 + j] : p[12 + j], 32);
      pf[c][0].g[0] = pkbf2(hh ? y[0] : p[0],  hh ? y[1] : p[1]);
      pf[c][0].g[1] = pkbf2(hh ? y[2] : p[2],  hh ? y[3] : p[3]);
      pf[c][0].g[2] = pkbf2(hh ? p[4] : y[0],  hh ? p[5] : y[1]);
      pf[c][0].g[3] = pkbf2(hh ? p[6] : y[2],  hh ? p[7] : y[3]);
      pf[c][1].g[0] = pkbf2(hh ? y[4] : p[8],  hh ? y[5] : p[9]);
      pf[c][1].g[1] = pkbf2(hh ? y[6] : p[10], hh ? y[7] : p[11]);
      pf[c][1].g[2] = pkbf2(hh ? p[12] : y[4], hh ? p[13] : y[5]);
      pf[c][1].g[3] = pkbf2(hh ? p[14] : y[6], hh ? p[15] : y[7]);
    }
    asm volatile("s_waitcnt vmcnt(0)" ::: "memory");
    __syncthreads();            // V(kt) + K(kt+1) staged; Kl[cur] reads done

    // PV: O^T[d][q] += V^T-chunk x P-chunk
#pragma unroll
    for (int c = 0; c < 4; ++c) {
#pragma unroll
      for (int k16 = 0; k16 < 2; ++k16) {
#pragma unroll
        for (int dhalf = 0; dhalf < 2; ++dhalf) {
          const int dv = dhalf * 32 + lq;
          FragU av;
          av.u = *(const uint4*)&Vt[dv * 128 + ((c * 32 + k16 * 16 + 8 * hh) ^ ((dv & 7) * 8))];
          acco[dhalf] = __builtin_amdgcn_mfma_f32_32x32x16_bf16(av.v, pf[c][k16].v, acco[dhalf], 0, 0, 0);
        }
      }
    }
    __syncthreads();            // Vt reads done before next iter's STAGE_V
  }

  // ctx epilogue: O[q = qbase+lq][d = h*64 + dhalf*32 + (r&3)+8*(r>>2)+4*hh]
  {
    const int h = bh % HH;
    const size_t cbase = ((size_t)b * SS + qbase + lq) * DD + h * 64;
#pragma unroll
    for (int dhalf = 0; dhalf < 2; ++dhalf) {
#pragma unroll
      for (int g = 0; g < 4; ++g) {
        float4 f4;
        f4.x = acco[dhalf][4 * g + 0]; f4.y = acco[dhalf][4 * g + 1];
        f4.z = acco[dhalf][4 * g + 2]; f4.w = acco[dhalf][4 * g + 3];
        *(float4*)(ctx + cbase + dhalf * 32 + 8 * g + 4 * hh) = f4;
      }
    }
  }
#undef STAGE_K
#undef STAGE_V
#undef QKT_CHUNK
}

extern "C" void kernel_launch(void* const* d_in, const int* in_sizes, int n_in,
                              void* d_out, int out_size, void* d_ws, size_t ws_size,
                              hipStream_t stream)
{
  const float* q   = (const float*)d_in[0];
  const float* k   = (const float*)d_in[1];
  const float* v   = (const float*)d_in[2];
  const void*  msk = d_in[3];
  const float* Wq  = (const float*)d_in[4];
  const float* bq  = (const float*)d_in[5];
  const float* Wk  = (const float*)d_in[6];
  const float* bk  = (const float*)d_in[7];
  const float* Wv  = (const float*)d_in[8];
  const float* bv  = (const float*)d_in[9];
  (void)in_sizes; (void)n_in; (void)out_size; (void)ws_size;

  const size_t NE = (size_t)BB * SS * DD;
  u16t* Qb = (u16t*)d_ws;
  u16t* Kb = Qb + NE;
  u16t* Vb = Kb + NE;
  int* flag = (int*)(Vb + NE);

  float* ctx   = (float*)d_out;
  float* probs = ctx + NE;

  detect_kernel<<<1, 256, 0, stream>>>((const u32t*)msk, flag);

  dim3 pg(BB * SS / 64, DD / 128);
  proj_qk_kernel<<<pg, 256, 0, stream>>>(q, Wq, bq, Qb);
  proj_qk_kernel<<<pg, 256, 0, stream>>>(k, Wk, bk, Kb);
  proj_v_kernel <<<pg, 256, 0, stream>>>(v, Wv, bv, Vb);

  attn_kernel<<<dim3(768), 256, 0, stream>>>(Qb, Kb, Vb, msk, flag, ctx, probs);
}